// Round 16
// baseline (80.188 us; speedup 1.0000x reference)
//
#include <hip/hip_runtime.h>
#include <math.h>

typedef _Float16 h16;
typedef _Float16 h8 __attribute__((ext_vector_type(8)));
typedef float f32x4 __attribute__((ext_vector_type(4)));

__device__ inline void gl2lds16(const void* g, void* l) {
  __builtin_amdgcn_global_load_lds(
      (const __attribute__((address_space(1))) void*)g,
      (__attribute__((address_space(3))) void*)l, 16, 0, 0);
}

// ---------------- fused fp32 -> fp16 conversion (hs + 4 weights) ----------------
__global__ __launch_bounds__(256) void f2h_all(
    const float* __restrict__ hs, const float* __restrict__ w0,
    const float* __restrict__ w1, const float* __restrict__ w2,
    const float* __restrict__ w3, h16* __restrict__ dst, int hsN) {
  int i = (blockIdx.x * 256 + threadIdx.x) * 8;
  const int tot = hsN + 4 * 1048576;
  if (i >= tot) return;
  const float* src;
  int off;
  if (i < hsN) {
    src = hs; off = i;
  } else {
    int k = i - hsN;
    int seg = k >> 20;
    off = k & 1048575;
    src = seg == 0 ? w0 : seg == 1 ? w1 : seg == 2 ? w2 : w3;
  }
  float4 a = *(const float4*)(src + off);
  float4 b = *(const float4*)(src + off + 4);
  h8 o;
  o[0] = (h16)a.x; o[1] = (h16)a.y; o[2] = (h16)a.z; o[3] = (h16)a.w;
  o[4] = (h16)b.x; o[5] = (h16)b.y; o[6] = (h16)b.z; o[7] = (h16)b.w;
  *(h8*)(dst + i) = o;
}

// ---------------- QKV GEMM: 128x96 tile, BK=64, grid 1024 -> 4 streams/CU ------
// Staged-bytes/stream model (3-for-3 validated): qkv13 was grid-capped at 3
// streams (768 blocks). BN=96 -> 1024 blocks = 4 streams/CU at the ~24 B/cyc/CU
// cap: 459 MB staged / 256 CU / 24 ~= 31 us. LDS 28 KB staging unioned with
// 26.6 KB Csh -> 4 blocks/CU. XCD chunk 8bm x 16bn bm-inner: A 2MB + hot B
// panel 192 KB, A-reuse distance 3.6 MB < 4 MB L2 (qkv13 profile, not r14's).
// 8-slot XOR swizzle both-sides (r13-exact mechanics).
__global__ __launch_bounds__(256, 4) void qkv16(
    const h16* __restrict__ A, const h16* __restrict__ Bw,
    const float* __restrict__ qb, const float* __restrict__ kb,
    const float* __restrict__ vb, h16* __restrict__ qo, h16* __restrict__ ko,
    h16* __restrict__ vo) {
  __shared__ __align__(16) char smem[28672];  // union
  h16* Ash = (h16*)smem;          // [128][64] = 16 KB
  h16* Bsh = Ash + 128 * 64;      // [96][64]  = 12 KB
  h16* Csh = (h16*)smem;          // [128][104] = 26.6 KB epilogue reuse

  const int tid = threadIdx.x;
  const int wid = tid >> 6, lane = tid & 63;
  const int lr = lane & 15, lg = lane >> 4;
  const int wr = wid >> 1, wc = wid & 1;          // 2x2 waves: 64 rows x 48 cols
  const int srow = tid >> 3;                      // staging row in call (0..31)
  const int csw = ((tid & 7) ^ (srow & 7)) * 8;   // inverse-swizzled source col

  // XCD chunks of the 32bm x 32bn grid: 4x2 XCD tiling, 8bm x 16bn, bm-inner
  const int xcd = blockIdx.x & 7;
  const int i = blockIdx.x >> 3;              // 0..127
  const int bm = (xcd & 3) * 8 + (i & 7);     // 0..31
  const int bn = (xcd >> 2) * 16 + (i >> 3);  // 0..31
  const int row0 = bm * 128;

  const h16* Ag = A + (size_t)row0 * 1024;
  const h16* Bg = Bw + (size_t)bn * 96 * 1024;

  auto stg = [&](const h16* g, h16* l, int rs, int kof) {
    gl2lds16(g + (size_t)(rs + srow) * 1024 + kof + csw, l + (rs + wid * 8) * 64);
  };
  auto ldf = [&](const h16* base, int row, int kk) -> h8 {
    return *(const h8*)(base + row * 64 + ((kk * 4 + lg) ^ (row & 7)) * 8);
  };

  f32x4 acc[4][3] = {};

  for (int t = 0; t < 16; ++t) {
    const int kof = t * 64;
    stg(Ag, Ash, 0, kof);  stg(Ag, Ash, 32, kof);
    stg(Ag, Ash, 64, kof); stg(Ag, Ash, 96, kof);
    stg(Bg, Bsh, 0, kof);  stg(Bg, Bsh, 32, kof);
    stg(Bg, Bsh, 64, kof);
    __syncthreads();  // drains vmcnt(0): tile staged, visible block-wide
    h8 af[4][2], bf[3][2];
#pragma unroll
    for (int m = 0; m < 4; ++m)
#pragma unroll
      for (int kk = 0; kk < 2; ++kk)
        af[m][kk] = ldf(Ash, wr * 64 + m * 16 + lr, kk);
#pragma unroll
    for (int n = 0; n < 3; ++n)
#pragma unroll
      for (int kk = 0; kk < 2; ++kk)
        bf[n][kk] = ldf(Bsh, wc * 48 + n * 16 + lr, kk);
    __builtin_amdgcn_s_setprio(1);
#pragma unroll
    for (int kk = 0; kk < 2; ++kk)
#pragma unroll
      for (int m = 0; m < 4; ++m)
#pragma unroll
        for (int n = 0; n < 3; ++n)
          acc[m][n] = __builtin_amdgcn_mfma_f32_16x16x32_f16(af[m][kk], bf[n][kk],
                                                             acc[m][n], 0, 0, 0);
    __builtin_amdgcn_s_setprio(0);
    __syncthreads();  // all reads done before next stage overwrites
  }

  // epilogue: bias + LDS bounce. 96-col tile may straddle q/k/v boundaries only
  // at 1024-multiples, which are 8-col-chunk aligned -> per-chunk select.
#pragma unroll
  for (int n = 0; n < 3; ++n) {
    const int ccol = wc * 48 + n * 16 + lr;
    const int gcol = bn * 96 + ccol;
    const int ts = gcol >> 10, jj = gcol & 1023;
    const float bv = (ts == 0 ? qb : (ts == 1 ? kb : vb))[jj];
#pragma unroll
    for (int m = 0; m < 4; ++m)
#pragma unroll
      for (int j = 0; j < 4; ++j)
        Csh[(wr * 64 + m * 16 + lg * 4 + j) * 104 + ccol] =
            (h16)(acc[m][n][j] + bv);
  }
  __syncthreads();
  // 128 rows x 12 h8-chunks = 1536 chunks, 6 per thread
#pragma unroll
  for (int p = 0; p < 6; ++p) {
    const int idx = p * 256 + tid;
    const int r = idx / 12, c = idx - r * 12;
    h8 v = *(const h8*)&Csh[r * 104 + c * 8];
    const int gcol = bn * 96 + c * 8;
    const int ts = gcol >> 10, dd = gcol & 1023;
    h16* outp = ts == 0 ? qo : (ts == 1 ? ko : vo);
    *(h8*)&outp[(size_t)(row0 + r) * 1024 + dd] = v;
  }
}

// ---------------- O-proj: 64x64 tile, BK=128 (r15 exact, at staging cap) -------
__global__ __launch_bounds__(256, 4) void oproj15(const h16* __restrict__ A,
                                                  const h16* __restrict__ Bw,
                                                  const float* __restrict__ b0,
                                                  float* __restrict__ Cf) {
  __shared__ __align__(16) h16 Ash[64 * 128];   // 16 KB
  __shared__ __align__(16) h16 Bsh[64 * 128];   // 16 KB

  const int tid = threadIdx.x;
  const int wid = tid >> 6, lane = tid & 63;
  const int lr = lane & 15, lg = lane >> 4;
  const int wr = wid >> 1, wc = wid & 1;          // wave-tile 32x32
  const int srow = tid >> 4;                      // staging row in call (0..15)
  const int csw = ((tid & 15) ^ (srow & 7)) * 8;  // inverse-swizzled source slot

  const int xcd = blockIdx.x & 7;
  const int i = blockIdx.x >> 3;        // 0..127
  const int bm = xcd * 8 + (i & 7);     // 0..63
  const int bn = i >> 3;                // 0..15
  const int row0 = bm * 64, col0 = bn * 64;

  const h16* Ag = A + (size_t)row0 * 1024;
  const h16* Bg = Bw + (size_t)col0 * 1024;

  auto stg = [&](const h16* g, h16* l, int rs, int kof) {
    gl2lds16(g + (size_t)(rs + srow) * 1024 + kof + csw, l + (rs + wid * 4) * 128);
  };
  auto ldf = [&](const h16* base, int row, int kk) -> h8 {
    return *(const h8*)(base + row * 128 + ((kk * 4 + lg) ^ (row & 7)) * 8);
  };

  f32x4 acc[2][2] = {};

  for (int t = 0; t < 8; ++t) {
    const int kof = t * 128;
    stg(Ag, Ash, 0, kof);  stg(Ag, Ash, 16, kof);
    stg(Ag, Ash, 32, kof); stg(Ag, Ash, 48, kof);
    stg(Bg, Bsh, 0, kof);  stg(Bg, Bsh, 16, kof);
    stg(Bg, Bsh, 32, kof); stg(Bg, Bsh, 48, kof);
    __syncthreads();
    h8 af[2][4], bf[2][4];
#pragma unroll
    for (int m = 0; m < 2; ++m)
#pragma unroll
      for (int kk = 0; kk < 4; ++kk)
        af[m][kk] = ldf(Ash, wr * 32 + m * 16 + lr, kk);
#pragma unroll
    for (int n = 0; n < 2; ++n)
#pragma unroll
      for (int kk = 0; kk < 4; ++kk)
        bf[n][kk] = ldf(Bsh, wc * 32 + n * 16 + lr, kk);
    __builtin_amdgcn_s_setprio(1);
#pragma unroll
    for (int kk = 0; kk < 4; ++kk)
#pragma unroll
      for (int m = 0; m < 2; ++m)
#pragma unroll
        for (int n = 0; n < 2; ++n)
          acc[m][n] = __builtin_amdgcn_mfma_f32_16x16x32_f16(af[m][kk], bf[n][kk],
                                                             acc[m][n], 0, 0, 0);
    __builtin_amdgcn_s_setprio(0);
    __syncthreads();
  }

#pragma unroll
  for (int n = 0; n < 2; ++n) {
    const int cidx = col0 + wc * 32 + n * 16 + lr;
    const float bv = b0[cidx];
#pragma unroll
    for (int m = 0; m < 2; ++m)
#pragma unroll
      for (int j = 0; j < 4; ++j) {
        const int r = row0 + wr * 32 + m * 16 + lg * 4 + j;
        Cf[(size_t)r * 1024 + cidx] = acc[m][n][j] + bv;
      }
  }
}

// ---------------- sliding-window attention ([B,S,E] inputs, r7 exact) ---------
__global__ __launch_bounds__(256) void swattn(const h16* __restrict__ Q,
                                              const h16* __restrict__ K,
                                              const h16* __restrict__ V,
                                              h16* __restrict__ O) {
  __shared__ __align__(16) h16 Ksh[128 * 72];
  __shared__ __align__(16) h16 Vsh[64 * 136];
  __shared__ __align__(16) h16 Psh[4][16 * 136];

  const int qb0 = blockIdx.x * 64;
  const int bh = blockIdx.y;
  const int b = bh >> 4, h = bh & 15;
  const int tid = threadIdx.x;
  const int wave = tid >> 6, lane = tid & 63;
  const int lr = lane & 15, lg = lane >> 4;

  const h16* Qb = Q + (size_t)b * 2048 * 1024 + h * 64;
  const h16* Kb = K + (size_t)b * 2048 * 1024 + h * 64;
  const h16* Vb = V + (size_t)b * 2048 * 1024 + h * 64;

#pragma unroll
  for (int i = 0; i < 4; ++i) {
    const int c = tid * 4 + i;
    const int row = c >> 3, c8 = c & 7;
    const int t = qb0 - 32 + row;
    h8 kv, vv;
    if (t >= 0 && t < 2048) {
      kv = *(const h8*)&Kb[(size_t)t * 1024 + c8 * 8];
      vv = *(const h8*)&Vb[(size_t)t * 1024 + c8 * 8];
    } else {
#pragma unroll
      for (int j = 0; j < 8; ++j) { kv[j] = (h16)0.f; vv[j] = (h16)0.f; }
    }
    *(h8*)&Ksh[row * 72 + c8 * 8] = kv;
#pragma unroll
    for (int j = 0; j < 8; ++j) Vsh[(c8 * 8 + j) * 136 + row] = vv[j];
  }
  __syncthreads();

  const int qrow = qb0 + wave * 16 + lr;
  h8 qa[2];
#pragma unroll
  for (int kk = 0; kk < 2; ++kk)
    qa[kk] = *(const h8*)&Qb[(size_t)qrow * 1024 + kk * 32 + lg * 8];

  f32x4 sacc[8] = {};
#pragma unroll
  for (int n = 0; n < 8; ++n)
#pragma unroll
    for (int kk = 0; kk < 2; ++kk) {
      h8 kb = *(const h8*)&Ksh[(n * 16 + lr) * 72 + kk * 32 + lg * 8];
      sacc[n] = __builtin_amdgcn_mfma_f32_16x16x32_f16(qa[kk], kb, sacc[n], 0, 0, 0);
    }

  float p[8][4];
#pragma unroll
  for (int j = 0; j < 4; ++j) {
    const int wrow = wave * 16 + lg * 4 + j;
    float mx = -1e30f;
#pragma unroll
    for (int n = 0; n < 8; ++n) {
      const int d = n * 16 + lr - wrow;
      float s = (d < 0 || d > 64) ? -1e30f : sacc[n][j] * 0.125f;
      p[n][j] = s;
      mx = fmaxf(mx, s);
    }
#pragma unroll
    for (int off = 1; off < 16; off <<= 1) mx = fmaxf(mx, __shfl_xor(mx, off, 64));
    float sum = 0.f;
#pragma unroll
    for (int n = 0; n < 8; ++n) {
      const float e = __expf(p[n][j] - mx);
      p[n][j] = e;
      sum += e;
    }
#pragma unroll
    for (int off = 1; off < 16; off <<= 1) sum += __shfl_xor(sum, off, 64);
    const float inv = 1.f / sum;
#pragma unroll
    for (int n = 0; n < 8; ++n) p[n][j] *= inv;
  }

#pragma unroll
  for (int n = 0; n < 8; ++n)
#pragma unroll
    for (int j = 0; j < 4; ++j)
      Psh[wave][(lg * 4 + j) * 136 + n * 16 + lr] = (h16)p[n][j];
  __syncthreads();

  f32x4 oacc[4] = {};
#pragma unroll
  for (int kk = 0; kk < 4; ++kk) {
    h8 pa = *(const h8*)&Psh[wave][lr * 136 + kk * 32 + lg * 8];
#pragma unroll
    for (int n = 0; n < 4; ++n) {
      h8 vb = *(const h8*)&Vsh[(n * 16 + lr) * 136 + kk * 32 + lg * 8];
      oacc[n] = __builtin_amdgcn_mfma_f32_16x16x32_f16(pa, vb, oacc[n], 0, 0, 0);
    }
  }

#pragma unroll
  for (int n = 0; n < 4; ++n)
#pragma unroll
    for (int j = 0; j < 4; ++j) {
      const int s = qb0 + wave * 16 + lg * 4 + j;
      const int d = n * 16 + lr;
      O[((size_t)b * 2048 + s) * 1024 + h * 64 + d] = (h16)oacc[n][j];
    }
}

extern "C" void kernel_launch(void* const* d_in, const int* in_sizes, int n_in,
                              void* d_out, int out_size, void* d_ws, size_t ws_size,
                              hipStream_t stream) {
  const float* hs = (const float*)d_in[0];
  const float* qw = (const float*)d_in[1];
  const float* qb = (const float*)d_in[2];
  const float* kw = (const float*)d_in[3];
  const float* kb = (const float*)d_in[4];
  const float* vw = (const float*)d_in[5];
  const float* vb = (const float*)d_in[6];
  const float* ow = (const float*)d_in[7];
  const float* ob = (const float*)d_in[8];

  const int M = in_sizes[0] / 1024;  // B * S = 4096

  h16* hsH = (h16*)d_ws;
  h16* wqkv = hsH + (size_t)M * 1024;
  h16* woH = wqkv + (size_t)3072 * 1024;
  h16* qH = woH + (size_t)1024 * 1024;  // [B,S,E]
  h16* kH = qH + (size_t)M * 1024;
  h16* vH = kH + (size_t)M * 1024;
  h16* attnH = vH + (size_t)M * 1024;   // [B,S,E]

  const int tot = M * 1024 + 4 * 1048576;
  f2h_all<<<(tot / 8 + 255) / 256, 256, 0, stream>>>(hs, qw, kw, vw, ow, hsH,
                                                     M * 1024);

  // QKV: 128x96 tiles, BK=64, grid 1024 -> 4 streams/CU
  qkv16<<<1024, 256, 0, stream>>>(hsH, wqkv, qb, kb, vb, qH, kH, vH);

  swattn<<<dim3(32, M / 2048 * 16), 256, 0, stream>>>(qH, kH, vH, attnH);

  // O-proj: 64x64 tiles, BK=128 (8 iters), grid 1024 -> 4 blocks/CU (r15)
  oproj15<<<1024, 256, 0, stream>>>(attnH, woH, ob, (float*)d_out);
}

// Round 18
// 77.396 us; speedup vs baseline: 1.0361x; 1.0361x over previous
//
#include <hip/hip_runtime.h>
#include <math.h>

typedef _Float16 h16;
typedef _Float16 h8 __attribute__((ext_vector_type(8)));
typedef float f32x4 __attribute__((ext_vector_type(4)));

__device__ inline void gl2lds16(const void* g, void* l) {
  __builtin_amdgcn_global_load_lds(
      (const __attribute__((address_space(1))) void*)g,
      (__attribute__((address_space(3))) void*)l, 16, 0, 0);
}

// ---------------- fp32 -> fp16 conversion (hs + q/k/v weights; ow moved) -------
__global__ __launch_bounds__(256) void f2h_3w(
    const float* __restrict__ hs, const float* __restrict__ w0,
    const float* __restrict__ w1, const float* __restrict__ w2,
    h16* __restrict__ dst, int hsN) {
  int i = (blockIdx.x * 256 + threadIdx.x) * 8;
  const int tot = hsN + 3 * 1048576;
  if (i >= tot) return;
  const float* src;
  int off;
  if (i < hsN) {
    src = hs; off = i;
  } else {
    int k = i - hsN;
    int seg = k >> 20;
    off = k & 1048575;
    src = seg == 0 ? w0 : seg == 1 ? w1 : w2;
  }
  float4 a = *(const float4*)(src + off);
  float4 b = *(const float4*)(src + off + 4);
  h8 o;
  o[0] = (h16)a.x; o[1] = (h16)a.y; o[2] = (h16)a.z; o[3] = (h16)a.w;
  o[4] = (h16)b.x; o[5] = (h16)b.y; o[6] = (h16)b.z; o[7] = (h16)b.w;
  *(h8*)(dst + i) = o;
}

// ---------------- QKV GEMM: 128x128 tile, BK=64 (r13 exact, frontier) ----------
// Frontier probed both directions: 3-stream/384MB (this) beats 4-stream/459MB
// (r16) and 6-block/L2-thrash (r14). Staging rate 17.3 B/cyc/CU.
__global__ __launch_bounds__(256) void qkv13(
    const h16* __restrict__ A, const h16* __restrict__ Bw,
    const float* __restrict__ qb, const float* __restrict__ kb,
    const float* __restrict__ vb, h16* __restrict__ qo, h16* __restrict__ ko,
    h16* __restrict__ vo) {
  __shared__ __align__(16) char smem[128 * 136 * 2];  // 34816 B union
  h16* Ash = (h16*)smem;          // [128][64] = 16 KB
  h16* Bsh = Ash + 128 * 64;      // [128][64] = 16 KB
  h16* Csh = (h16*)smem;          // [128][136] epilogue reuse

  const int tid = threadIdx.x;
  const int wid = tid >> 6, lane = tid & 63;
  const int lr = lane & 15, lg = lane >> 4;
  const int wr = wid >> 1, wc = wid & 1;
  const int srow = tid >> 3;                      // staging row in call (0..31)
  const int csw = ((tid & 7) ^ (srow & 7)) * 8;   // inverse-swizzled source col

  const int wg = (blockIdx.x & 7) * 96 + (blockIdx.x >> 3);
  const int bm = wg & 31, bn = wg >> 5;
  const int row0 = bm * 128, col0 = bn * 128;

  const h16* Ag = A + (size_t)row0 * 1024;
  const h16* Bg = Bw + (size_t)col0 * 1024;

  auto stg = [&](const h16* g, h16* l, int rs, int kof) {
    gl2lds16(g + (size_t)(rs + srow) * 1024 + kof + csw, l + (rs + wid * 8) * 64);
  };
  auto ldf = [&](const h16* base, int row, int kk) -> h8 {
    return *(const h8*)(base + row * 64 + ((kk * 4 + lg) ^ (row & 7)) * 8);
  };

  f32x4 acc[4][4] = {};

  for (int t = 0; t < 16; ++t) {
    const int kof = t * 64;
    stg(Ag, Ash, 0, kof);  stg(Ag, Ash, 32, kof);
    stg(Ag, Ash, 64, kof); stg(Ag, Ash, 96, kof);
    stg(Bg, Bsh, 0, kof);  stg(Bg, Bsh, 32, kof);
    stg(Bg, Bsh, 64, kof); stg(Bg, Bsh, 96, kof);
    __syncthreads();
    h8 af[4][2], bf[4][2];
#pragma unroll
    for (int m = 0; m < 4; ++m)
#pragma unroll
      for (int kk = 0; kk < 2; ++kk)
        af[m][kk] = ldf(Ash, wr * 64 + m * 16 + lr, kk);
#pragma unroll
    for (int n = 0; n < 4; ++n)
#pragma unroll
      for (int kk = 0; kk < 2; ++kk)
        bf[n][kk] = ldf(Bsh, wc * 64 + n * 16 + lr, kk);
    __builtin_amdgcn_s_setprio(1);
#pragma unroll
    for (int kk = 0; kk < 2; ++kk)
#pragma unroll
      for (int m = 0; m < 4; ++m)
#pragma unroll
        for (int n = 0; n < 4; ++n)
          acc[m][n] = __builtin_amdgcn_mfma_f32_16x16x32_f16(af[m][kk], bf[n][kk],
                                                             acc[m][n], 0, 0, 0);
    __builtin_amdgcn_s_setprio(0);
    __syncthreads();
  }

  const int tsel = bn >> 3;
  const int colseg = (bn & 7) * 128;
  const float* bp = tsel == 0 ? qb : (tsel == 1 ? kb : vb);
  h16* outp = tsel == 0 ? qo : (tsel == 1 ? ko : vo);

#pragma unroll
  for (int n = 0; n < 4; ++n) {
    const int ccol = wc * 64 + n * 16 + lr;
    const float bv = bp[colseg + ccol];
#pragma unroll
    for (int m = 0; m < 4; ++m)
#pragma unroll
      for (int j = 0; j < 4; ++j)
        Csh[(wr * 64 + m * 16 + lg * 4 + j) * 136 + ccol] =
            (h16)(acc[m][n][j] + bv);
  }
  __syncthreads();
#pragma unroll
  for (int p = 0; p < 8; ++p) {
    const int idx = p * 256 + tid;
    const int r = idx >> 4, c = idx & 15;
    h8 v = *(const h8*)&Csh[r * 136 + c * 8];
    *(h8*)&outp[(size_t)(row0 + r) * 1024 + colseg + c * 8] = v;
  }
}

// ---------------- O-proj: 64x64 tile, BK=128 (r15 exact, at staging cap) -------
__global__ __launch_bounds__(256, 4) void oproj15(const h16* __restrict__ A,
                                                  const h16* __restrict__ Bw,
                                                  const float* __restrict__ b0,
                                                  float* __restrict__ Cf) {
  __shared__ __align__(16) h16 Ash[64 * 128];   // 16 KB
  __shared__ __align__(16) h16 Bsh[64 * 128];   // 16 KB

  const int tid = threadIdx.x;
  const int wid = tid >> 6, lane = tid & 63;
  const int lr = lane & 15, lg = lane >> 4;
  const int wr = wid >> 1, wc = wid & 1;          // wave-tile 32x32
  const int srow = tid >> 4;                      // staging row in call (0..15)
  const int csw = ((tid & 15) ^ (srow & 7)) * 8;  // inverse-swizzled source slot

  const int xcd = blockIdx.x & 7;
  const int i = blockIdx.x >> 3;        // 0..127
  const int bm = xcd * 8 + (i & 7);     // 0..63
  const int bn = i >> 3;                // 0..15
  const int row0 = bm * 64, col0 = bn * 64;

  const h16* Ag = A + (size_t)row0 * 1024;
  const h16* Bg = Bw + (size_t)col0 * 1024;

  auto stg = [&](const h16* g, h16* l, int rs, int kof) {
    gl2lds16(g + (size_t)(rs + srow) * 1024 + kof + csw, l + (rs + wid * 4) * 128);
  };
  auto ldf = [&](const h16* base, int row, int kk) -> h8 {
    return *(const h8*)(base + row * 128 + ((kk * 4 + lg) ^ (row & 7)) * 8);
  };

  f32x4 acc[2][2] = {};

  for (int t = 0; t < 8; ++t) {
    const int kof = t * 128;
    stg(Ag, Ash, 0, kof);  stg(Ag, Ash, 16, kof);
    stg(Ag, Ash, 32, kof); stg(Ag, Ash, 48, kof);
    stg(Bg, Bsh, 0, kof);  stg(Bg, Bsh, 16, kof);
    stg(Bg, Bsh, 32, kof); stg(Bg, Bsh, 48, kof);
    __syncthreads();
    h8 af[2][4], bf[2][4];
#pragma unroll
    for (int m = 0; m < 2; ++m)
#pragma unroll
      for (int kk = 0; kk < 4; ++kk)
        af[m][kk] = ldf(Ash, wr * 32 + m * 16 + lr, kk);
#pragma unroll
    for (int n = 0; n < 2; ++n)
#pragma unroll
      for (int kk = 0; kk < 4; ++kk)
        bf[n][kk] = ldf(Bsh, wc * 32 + n * 16 + lr, kk);
    __builtin_amdgcn_s_setprio(1);
#pragma unroll
    for (int kk = 0; kk < 4; ++kk)
#pragma unroll
      for (int m = 0; m < 2; ++m)
#pragma unroll
        for (int n = 0; n < 2; ++n)
          acc[m][n] = __builtin_amdgcn_mfma_f32_16x16x32_f16(af[m][kk], bf[n][kk],
                                                             acc[m][n], 0, 0, 0);
    __builtin_amdgcn_s_setprio(0);
    __syncthreads();
  }

#pragma unroll
  for (int n = 0; n < 2; ++n) {
    const int cidx = col0 + wc * 32 + n * 16 + lr;
    const float bv = b0[cidx];
#pragma unroll
    for (int m = 0; m < 2; ++m)
#pragma unroll
      for (int j = 0; j < 4; ++j) {
        const int r = row0 + wr * 32 + m * 16 + lg * 4 + j;
        Cf[(size_t)r * 1024 + cidx] = acc[m][n][j] + bv;
      }
  }
}

// ---------------- sliding-window attention + fused ow conversion ---------------
// r7-exact attention body; appended ow fp32->fp16. Grid is 32 x 32 = 1024
// blocks (B=2); only the first 131072 threads (gid*8 < 1M) convert -- the
// unguarded version read 4 MB OOB (r17 crash).
__global__ __launch_bounds__(256) void swattn(const h16* __restrict__ Q,
                                              const h16* __restrict__ K,
                                              const h16* __restrict__ V,
                                              h16* __restrict__ O,
                                              const float* __restrict__ ow,
                                              h16* __restrict__ woH) {
  __shared__ __align__(16) h16 Ksh[128 * 72];
  __shared__ __align__(16) h16 Vsh[64 * 136];
  __shared__ __align__(16) h16 Psh[4][16 * 136];

  const int qb0 = blockIdx.x * 64;
  const int bh = blockIdx.y;
  const int b = bh >> 4, h = bh & 15;
  const int tid = threadIdx.x;
  const int wave = tid >> 6, lane = tid & 63;
  const int lr = lane & 15, lg = lane >> 4;

  const h16* Qb = Q + (size_t)b * 2048 * 1024 + h * 64;
  const h16* Kb = K + (size_t)b * 2048 * 1024 + h * 64;
  const h16* Vb = V + (size_t)b * 2048 * 1024 + h * 64;

#pragma unroll
  for (int i = 0; i < 4; ++i) {
    const int c = tid * 4 + i;
    const int row = c >> 3, c8 = c & 7;
    const int t = qb0 - 32 + row;
    h8 kv, vv;
    if (t >= 0 && t < 2048) {
      kv = *(const h8*)&Kb[(size_t)t * 1024 + c8 * 8];
      vv = *(const h8*)&Vb[(size_t)t * 1024 + c8 * 8];
    } else {
#pragma unroll
      for (int j = 0; j < 8; ++j) { kv[j] = (h16)0.f; vv[j] = (h16)0.f; }
    }
    *(h8*)&Ksh[row * 72 + c8 * 8] = kv;
#pragma unroll
    for (int j = 0; j < 8; ++j) Vsh[(c8 * 8 + j) * 136 + row] = vv[j];
  }
  __syncthreads();

  const int qrow = qb0 + wave * 16 + lr;
  h8 qa[2];
#pragma unroll
  for (int kk = 0; kk < 2; ++kk)
    qa[kk] = *(const h8*)&Qb[(size_t)qrow * 1024 + kk * 32 + lg * 8];

  f32x4 sacc[8] = {};
#pragma unroll
  for (int n = 0; n < 8; ++n)
#pragma unroll
    for (int kk = 0; kk < 2; ++kk) {
      h8 kb = *(const h8*)&Ksh[(n * 16 + lr) * 72 + kk * 32 + lg * 8];
      sacc[n] = __builtin_amdgcn_mfma_f32_16x16x32_f16(qa[kk], kb, sacc[n], 0, 0, 0);
    }

  float p[8][4];
#pragma unroll
  for (int j = 0; j < 4; ++j) {
    const int wrow = wave * 16 + lg * 4 + j;
    float mx = -1e30f;
#pragma unroll
    for (int n = 0; n < 8; ++n) {
      const int d = n * 16 + lr - wrow;
      float s = (d < 0 || d > 64) ? -1e30f : sacc[n][j] * 0.125f;
      p[n][j] = s;
      mx = fmaxf(mx, s);
    }
#pragma unroll
    for (int off = 1; off < 16; off <<= 1) mx = fmaxf(mx, __shfl_xor(mx, off, 64));
    float sum = 0.f;
#pragma unroll
    for (int n = 0; n < 8; ++n) {
      const float e = __expf(p[n][j] - mx);
      p[n][j] = e;
      sum += e;
    }
#pragma unroll
    for (int off = 1; off < 16; off <<= 1) sum += __shfl_xor(sum, off, 64);
    const float inv = 1.f / sum;
#pragma unroll
    for (int n = 0; n < 8; ++n) p[n][j] *= inv;
  }

#pragma unroll
  for (int n = 0; n < 8; ++n)
#pragma unroll
    for (int j = 0; j < 4; ++j)
      Psh[wave][(lg * 4 + j) * 136 + n * 16 + lr] = (h16)p[n][j];
  __syncthreads();

  f32x4 oacc[4] = {};
#pragma unroll
  for (int kk = 0; kk < 4; ++kk) {
    h8 pa = *(const h8*)&Psh[wave][lr * 136 + kk * 32 + lg * 8];
#pragma unroll
    for (int n = 0; n < 4; ++n) {
      h8 vb = *(const h8*)&Vsh[(n * 16 + lr) * 136 + kk * 32 + lg * 8];
      oacc[n] = __builtin_amdgcn_mfma_f32_16x16x32_f16(pa, vb, oacc[n], 0, 0, 0);
    }
  }

#pragma unroll
  for (int n = 0; n < 4; ++n)
#pragma unroll
    for (int j = 0; j < 4; ++j) {
      const int s = qb0 + wave * 16 + lg * 4 + j;
      const int d = n * 16 + lr;
      O[((size_t)b * 2048 + s) * 1024 + h * 64 + d] = (h16)oacc[n][j];
    }

  // fused ow conversion: 1M elems = 131072 h8-chunks; guard against the
  // 1024-block grid (262144 threads) overrunning the buffer (r17 bug).
  {
    const int gid = (blockIdx.y * 32 + blockIdx.x) * 256 + tid;
    if (gid < 131072) {
      const int i = gid * 8;
      float4 a = *(const float4*)(ow + i);
      float4 bq = *(const float4*)(ow + i + 4);
      h8 o;
      o[0] = (h16)a.x; o[1] = (h16)a.y; o[2] = (h16)a.z; o[3] = (h16)a.w;
      o[4] = (h16)bq.x; o[5] = (h16)bq.y; o[6] = (h16)bq.z; o[7] = (h16)bq.w;
      *(h8*)(woH + i) = o;
    }
  }
}

extern "C" void kernel_launch(void* const* d_in, const int* in_sizes, int n_in,
                              void* d_out, int out_size, void* d_ws, size_t ws_size,
                              hipStream_t stream) {
  const float* hs = (const float*)d_in[0];
  const float* qw = (const float*)d_in[1];
  const float* qb = (const float*)d_in[2];
  const float* kw = (const float*)d_in[3];
  const float* kb = (const float*)d_in[4];
  const float* vw = (const float*)d_in[5];
  const float* vb = (const float*)d_in[6];
  const float* ow = (const float*)d_in[7];
  const float* ob = (const float*)d_in[8];

  const int M = in_sizes[0] / 1024;  // B * S = 4096

  h16* hsH = (h16*)d_ws;
  h16* wqkv = hsH + (size_t)M * 1024;
  h16* woH = wqkv + (size_t)3072 * 1024;
  h16* qH = woH + (size_t)1024 * 1024;  // [B,S,E]
  h16* kH = qH + (size_t)M * 1024;
  h16* vH = kH + (size_t)M * 1024;
  h16* attnH = vH + (size_t)M * 1024;   // [B,S,E]

  const int tot = M * 1024 + 3 * 1048576;
  f2h_3w<<<(tot / 8 + 255) / 256, 256, 0, stream>>>(hs, qw, kw, vw, hsH,
                                                    M * 1024);

  // QKV: 128x128 tiles, BK=64 (16 iters), 768 blocks, 3/CU (frontier)
  qkv13<<<768, 256, 0, stream>>>(hsH, wqkv, qb, kb, vb, qH, kH, vH);

  // attention + fused ow conversion (woH consumed only by the next launch)
  swattn<<<dim3(32, M / 2048 * 16), 256, 0, stream>>>(qH, kH, vH, attnH, ow, woH);

  // O-proj: 64x64 tiles, BK=128 (8 iters), grid 1024 -> 4 blocks/CU
  oproj15<<<1024, 256, 0, stream>>>(attnH, woH, ob, (float*)d_out);
}